// Round 7
// baseline (142.681 us; speedup 1.0000x reference)
//
#include <hip/hip_runtime.h>

typedef short bf16x8 __attribute__((ext_vector_type(8)));
typedef short bf16x4 __attribute__((ext_vector_type(4)));
typedef float f32x4  __attribute__((ext_vector_type(4)));

#define NSPAN 2000
#define DSPAN 1220
#define NPAIR 65536
#define HID   150
#define HP    160          // padded hidden width
#define TW    320          // T row: [0,160) A-proj, [160,320) B-proj
#define NKS   78           // total k-steps of 32 (K = 2496 = 2 x 1248)
#define NKH   39           // k-steps per half (g half / g^2 half)
#define NMT   128          // 2048/16 row tiles
#define NNT   20           // 320/16 col tiles
#define KC    13           // k-split chunks (78 = 13*6), 6 ks each  [R4-proven]
#define NCMB  189          // 9*7*3 phi combos

// prep_all grid sections
#define GA 1248            // A-fragments
#define GB 390             // Wc-fragments
#define GC 119             // combo phi table (189*160 = 30240, bf16)
#define GD 13              // W2 fragments (3200)
#define GE 160             // zero T (160000 float4)

static __device__ __forceinline__ short f2bf(float x) {
  unsigned u = __builtin_bit_cast(unsigned, x);
  u = (u + 0x7FFFu + ((u >> 16) & 1u)) >> 16;   // RNE
  return (short)u;
}
static __device__ __forceinline__ float bf2f(short s) {
  unsigned u = ((unsigned)(unsigned short)s) << 16;
  return __builtin_bit_cast(float, u);
}

// ---------------- prep_all: everything except the GEMMs ----------------
__global__ __launch_bounds__(256)
void prep_all(const float* __restrict__ g, const float* __restrict__ W1,
              const float* __restrict__ b1, const float* __restrict__ de,
              const float* __restrict__ ge, const float* __restrict__ se,
              const float* __restrict__ W2, short* __restrict__ A_fr,
              short* __restrict__ Wc_fr, short* __restrict__ combo,
              short* __restrict__ W2_fr, float* __restrict__ T) {
  int b = blockIdx.x;
  int t = threadIdx.x;
  if (b < GA) {                               // ---- A fragments ----
    int tid = b * 256 + t;                    // 1248*256 = 128*39*64 exact
    int l  = tid & 63;
    int t2 = tid >> 6;
    int ks = t2 % NKH;
    int mt = t2 / NKH;
    int m  = mt * 16 + (l & 15);
    int k0 = ks * 32 + ((l >> 4) << 3);
    float x[8];
    if (m < NSPAN && k0 + 8 <= DSPAN) {       // g rows 16B-aligned
      float4 f0 = *(const float4*)&g[m * DSPAN + k0];
      float4 f1 = *(const float4*)&g[m * DSPAN + k0 + 4];
      x[0]=f0.x; x[1]=f0.y; x[2]=f0.z; x[3]=f0.w;
      x[4]=f1.x; x[5]=f1.y; x[6]=f1.z; x[7]=f1.w;
    } else {
#pragma unroll
      for (int i = 0; i < 8; ++i) {
        int k = k0 + i;
        x[i] = (m < NSPAN && k < DSPAN) ? g[m * DSPAN + k] : 0.f;
      }
    }
    short v1[8], v2[8];
#pragma unroll
    for (int i = 0; i < 8; ++i) { v1[i] = f2bf(x[i]); v2[i] = f2bf(x[i] * x[i]); }
    size_t o1 = ((size_t)(mt * NKS + ks) * 64 + l) * 8;
    *(bf16x8*)(A_fr + o1) = *(const bf16x8*)v1;
    *(bf16x8*)(A_fr + o1 + (size_t)NKH * 512) = *(const bf16x8*)v2;
  } else if (b < GA + GB) {                   // ---- Wc fragments ----
    int tid = (b - GA) * 256 + t;             // 390*256 = 20*78*64 exact
    int l  = tid & 63;
    int t2 = tid >> 6;
    int ks = t2 % NKS;
    int nt = t2 / NKS;
    int n  = nt * 16 + (l & 15);
    int k0 = ks * 32 + ((l >> 4) << 3);
    short v[8];
#pragma unroll
    for (int i = 0; i < 8; ++i) {
      int k = k0 + i;
      float x = 0.f;
      if (n < HID) {
        if (k < DSPAN)                     x = W1[k * HID + n];
      } else if (n >= HP && n < HP + HID) {
        int j = n - HP;
        if (k < DSPAN)                     x = W1[(DSPAN + k) * HID + j];
        else if (k >= 1248 && k < 2468)    x = W1[(1192 + k) * HID + j];
      }
      v[i] = f2bf(x);
    }
    *(bf16x8*)(Wc_fr + (size_t)tid * 8) = *(const bf16x8*)v;
  } else if (b < GA + GB + GC) {              // ---- combined phi table (bf16) ----
    int idx = (b - GA - GB) * 256 + t;
    if (idx < NCMB * HP) {
      int c = idx / HP;
      int j = idx - c * HP;
      float v = 0.f;
      if (j < HID) {
        int si = c % 3;
        int t2 = c / 3;
        int gi = t2 % 7;
        int bi = t2 / 7;
        v = b1[j];
        const float* dp = de + bi * 20;
        const float* gp = ge + gi * 20;
        const float* sp = se + si * 20;
#pragma unroll
        for (int e = 0; e < 20; ++e) {
          v += dp[e] * W1[(3660 + e) * HID + j];
          v += gp[e] * W1[(3680 + e) * HID + j];
          v += sp[e] * W1[(3700 + e) * HID + j];
        }
      }
      combo[idx] = f2bf(v);
    }
  } else if (b < GA + GB + GC + GD) {         // ---- W2 fragments ----
    int tid = (b - GA - GB - GC) * 256 + t;
    if (tid < 3200) {
      int l  = tid & 63;
      int t2 = tid >> 6;
      int ks = t2 % 5;
      int jt = t2 / 5;
      int n  = jt * 16 + (l & 15);
      int k0 = ks * 32 + ((l >> 4) << 3);
      short v[8];
#pragma unroll
      for (int i = 0; i < 8; ++i) {
        int k = k0 + i;
        float x = (k < HID && n < HID) ? W2[k * HID + n] : 0.f;
        v[i] = f2bf(x);
      }
      *(bf16x8*)(W2_fr + (size_t)tid * 8) = *(const bf16x8*)v;
    }
  } else {                                    // ---- zero T ----
    int idx = (b - GA - GB - GC - GD) * 256 + t;
    f32x4 z = {0.f, 0.f, 0.f, 0.f};
    if (idx < NSPAN * TW / 4) ((f32x4*)T)[idx] = z;
  }
}

// ---------- span GEMM: T += A_cat @ Wc, K-split x13, fp32 atomicAdd ----------
__global__ __launch_bounds__(256)
void span_gemm(const short* __restrict__ A_fr, const short* __restrict__ Wc_fr,
               float* __restrict__ T) {
  int t = threadIdx.x, w = t >> 6, l = t & 63;
  int mt  = blockIdx.y * 4 + w;
  int ntb = blockIdx.x * 4;
  int ksb = blockIdx.z * 6;
  const short* pa = A_fr + ((size_t)(mt * NKS + ksb) * 64 + l) * 8;
  const short* pb = Wc_fr + ((size_t)(ntb * NKS + ksb) * 64 + l) * 8;
  f32x4 a0 = {0.f, 0.f, 0.f, 0.f}, a1 = a0, a2 = a0, a3 = a0;
#pragma unroll
  for (int ks = 0; ks < 6; ++ks) {
    bf16x8 a  = *(const bf16x8*)pa;
    bf16x8 b0 = *(const bf16x8*)pb;
    bf16x8 b1 = *(const bf16x8*)(pb + (size_t)NKS * 512);
    bf16x8 b2 = *(const bf16x8*)(pb + (size_t)2 * NKS * 512);
    bf16x8 b3 = *(const bf16x8*)(pb + (size_t)3 * NKS * 512);
    a0 = __builtin_amdgcn_mfma_f32_16x16x32_bf16(a, b0, a0, 0, 0, 0);
    a1 = __builtin_amdgcn_mfma_f32_16x16x32_bf16(a, b1, a1, 0, 0, 0);
    a2 = __builtin_amdgcn_mfma_f32_16x16x32_bf16(a, b2, a2, 0, 0, 0);
    a3 = __builtin_amdgcn_mfma_f32_16x16x32_bf16(a, b3, a3, 0, 0, 0);
    pa += 512; pb += 512;
  }
  int col = l & 15, row4 = (l >> 4) << 2;
  f32x4 acc[4] = {a0, a1, a2, a3};
#pragma unroll
  for (int r = 0; r < 4; ++r) {
    int m = mt * 16 + row4 + r;
    if (m < NSPAN) {
#pragma unroll
      for (int j = 0; j < 4; ++j)
        atomicAdd(&T[m * TW + (ntb + j) * 16 + col], acc[j][r]);
    }
  }
}

// ---------- convert_T: fp32 T -> bf16 Tb ----------
__global__ __launch_bounds__(256)
void convert_T(const float* __restrict__ Tf, short* __restrict__ Tb) {
  int i = (blockIdx.x * 256 + threadIdx.x) * 4;  // 625 blocks: 160000 float4 exact
  float4 v = *(const float4*)(Tf + i);
  bf16x4 r;
  r[0] = f2bf(v.x); r[1] = f2bf(v.y); r[2] = f2bf(v.z); r[3] = f2bf(v.w);
  *(bf16x4*)(Tb + i) = r;
}

// ---------- pair kernel: bf16 gather -> A-frags -> MFMA -> score ----------
// Lane l of wave w serves pair base + w*16 + (l&15) at k-offset (l>>4)*8:
// exactly the MFMA A-fragment element set. 15 independent 16B gathers/lane.
__global__ __launch_bounds__(256)
void pair_kernel(const short* __restrict__ Tb, const short* __restrict__ combo,
                 const short* __restrict__ W2_fr,
                 const float* __restrict__ b2, const float* __restrict__ W3,
                 const float* __restrict__ b3, const float* __restrict__ s_m,
                 const int* __restrict__ m_ids, const int* __restrict__ a_ids,
                 const int* __restrict__ dist, const int* __restrict__ genre,
                 const int* __restrict__ spk, float* __restrict__ out) {
  __shared__ float w3s[HP], b2s[HP], sm2[64];

  int t = threadIdx.x, w = t >> 6, l = t & 63;
  int base = blockIdx.x * 64;

  if (t < 64) {
    int p = base + t;
    sm2[t] = s_m[m_ids[p]] + s_m[a_ids[p]];
  }
  if (t < HP) {
    w3s[t] = (t < HID) ? W3[t] : 0.f;
    b2s[t] = (t < HID) ? b2[t] : 0.f;
  }
  float b3v = b3[0];
  __syncthreads();          // covers sm2/w3s/b2s only

  int pr = l & 15;          // pair row within wave
  int q  = l >> 4;          // quad -> k-offset q*8
  int p  = base + w * 16 + pr;
  int m = m_ids[p], a = a_ids[p];
  int d = dist[p];
  int bb = (d >= 2) + (d >= 3) + (d >= 4) + (d >= 5) + (d >= 8) +
           (d >= 16) + (d >= 32) + (d >= 64);
  int co = ((bb * 7 + genre[p]) * 3 + spk[p]) * HP;

  const short* pA = Tb + m * TW + q * 8;
  const short* pB = Tb + a * TW + HP + q * 8;
  const short* pC = combo + co + q * 8;

  bf16x8 af[5];
#pragma unroll
  for (int ks = 0; ks < 5; ++ks) {
    bf16x8 va = *(const bf16x8*)(pA + ks * 32);
    bf16x8 vb = *(const bf16x8*)(pB + ks * 32);
    bf16x8 vc = *(const bf16x8*)(pC + ks * 32);
    short v[8];
#pragma unroll
    for (int i = 0; i < 8; ++i)
      v[i] = f2bf(fmaxf(bf2f(va[i]) + bf2f(vb[i]) + bf2f(vc[i]), 0.f));
    af[ks] = *(const bf16x8*)v;
  }

  f32x4 acc[10];
#pragma unroll
  for (int jt = 0; jt < 10; ++jt) acc[jt] = {0.f, 0.f, 0.f, 0.f};

  const short* pw = W2_fr + l * 8;
#pragma unroll
  for (int jt = 0; jt < 10; ++jt) {
#pragma unroll
    for (int ks = 0; ks < 5; ++ks) {
      bf16x8 bfr = *(const bf16x8*)(pw + (size_t)(jt * 5 + ks) * 512);
      acc[jt] = __builtin_amdgcn_mfma_f32_16x16x32_bf16(af[ks], bfr, acc[jt], 0, 0, 0);
    }
  }

  // epilogue: relu(h2 + b2) . W3, reduce over the 16 col-lanes
  float part[4] = {0.f, 0.f, 0.f, 0.f};
  int cl = l & 15;
#pragma unroll
  for (int jt = 0; jt < 10; ++jt) {
    int n = jt * 16 + cl;
    float w3v = w3s[n], b2v = b2s[n];
#pragma unroll
    for (int r = 0; r < 4; ++r) part[r] += fmaxf(acc[jt][r] + b2v, 0.f) * w3v;
  }
#pragma unroll
  for (int off = 8; off >= 1; off >>= 1) {
#pragma unroll
    for (int r = 0; r < 4; ++r) part[r] += __shfl_xor(part[r], off, 64);
  }
  if (cl == 0) {
    int rowb = q << 2;
#pragma unroll
    for (int r = 0; r < 4; ++r) {
      int pl = w * 16 + rowb + r;
      out[base + pl] = sm2[pl] + part[r] + b3v;
    }
  }
}

extern "C" void kernel_launch(void* const* d_in, const int* in_sizes, int n_in,
                              void* d_out, int out_size, void* d_ws, size_t ws_size,
                              hipStream_t stream) {
  const float* g     = (const float*)d_in[0];
  const float* s_m   = (const float*)d_in[1];
  const int*   m_ids = (const int*)d_in[2];
  const int*   a_ids = (const int*)d_in[3];
  const int*   dist  = (const int*)d_in[4];
  const int*   genre = (const int*)d_in[5];
  const int*   spk   = (const int*)d_in[6];
  const float* de    = (const float*)d_in[7];
  const float* ge    = (const float*)d_in[8];
  const float* se    = (const float*)d_in[9];
  const float* W1    = (const float*)d_in[10];
  const float* b1    = (const float*)d_in[11];
  const float* W2    = (const float*)d_in[12];
  const float* b2    = (const float*)d_in[13];
  const float* W3    = (const float*)d_in[14];
  const float* b3    = (const float*)d_in[15];
  float* out = (float*)d_out;

  float* Tf    = (float*)d_ws;                    // 2000*320 f32 = 2.56 MB
  short* Tb    = (short*)(Tf + NSPAN * TW);       // 2000*320 bf16 = 1.28 MB
  short* combo = Tb + NSPAN * TW;                 // 189*160 bf16
  short* A_fr  = combo + NCMB * HP;               // 128*78*512 bf16 = 10.22 MB
  short* Wc_fr = A_fr + (size_t)NMT * NKS * 512;  // 20*78*512 bf16 = 1.60 MB
  short* W2_fr = Wc_fr + (size_t)NNT * NKS * 512; // 3200*8 bf16

  prep_all<<<GA + GB + GC + GD + GE, 256, 0, stream>>>(
      g, W1, b1, de, ge, se, W2, A_fr, Wc_fr, combo, W2_fr, Tf);
  span_gemm<<<dim3(5, 32, KC), 256, 0, stream>>>(A_fr, Wc_fr, Tf);
  convert_T<<<625, 256, 0, stream>>>(Tf, Tb);
  pair_kernel<<<NPAIR / 64, 256, 0, stream>>>(Tb, combo, W2_fr, b2, W3, b3, s_m,
                                              m_ids, a_ids, dist, genre, spk, out);
}

// Round 8
// 122.799 us; speedup vs baseline: 1.1619x; 1.1619x over previous
//
#include <hip/hip_runtime.h>

typedef short bf16x8 __attribute__((ext_vector_type(8)));
typedef short bf16x4 __attribute__((ext_vector_type(4)));
typedef float f32x4  __attribute__((ext_vector_type(4)));

#define NSPAN 2000
#define DSPAN 1220
#define NPAIR 65536
#define HID   150
#define HP    160          // padded hidden width
#define TW    320          // T row: [0,160) A-proj, [160,320) B-proj
#define NKS   78           // total k-steps of 32 (K = 2496 = 2 x 1248)
#define NKH   39           // k-steps per half (g half / g^2 half)
#define NMT   128          // 2048/16 row tiles
#define NNT   20           // 320/16 col tiles
#define KC    6            // k-split chunks (78 = 6*13), 13 ks each [R4-proven]
#define H1S   168          // h1 bf16 row stride (336 B, 16B aligned)
#define NCMB  189          // 9*7*3 phi combos
#define TSZ   (NSPAN * TW) // 640000 elements per T image

// prep_all grid sections
#define GA 1248            // A-fragments
#define GB 390             // Wc-fragments
#define GC 119             // combo phi table (189*160, bf16)
#define GD 13              // W2 fragments (3200)

static __device__ __forceinline__ short f2bf(float x) {
  unsigned u = __builtin_bit_cast(unsigned, x);
  u = (u + 0x7FFFu + ((u >> 16) & 1u)) >> 16;   // RNE
  return (short)u;
}
static __device__ __forceinline__ float bf2f(short s) {
  unsigned u = ((unsigned)(unsigned short)s) << 16;
  return __builtin_bit_cast(float, u);
}

// ---------------- prep_all: fragments + combo table ----------------
__global__ __launch_bounds__(256)
void prep_all(const float* __restrict__ g, const float* __restrict__ W1,
              const float* __restrict__ b1, const float* __restrict__ de,
              const float* __restrict__ ge, const float* __restrict__ se,
              const float* __restrict__ W2, short* __restrict__ A_fr,
              short* __restrict__ Wc_fr, short* __restrict__ combo,
              short* __restrict__ W2_fr) {
  int b = blockIdx.x;
  int t = threadIdx.x;
  if (b < GA) {                               // ---- A fragments ----
    int tid = b * 256 + t;                    // 1248*256 = 128*39*64 exact
    int l  = tid & 63;
    int t2 = tid >> 6;
    int ks = t2 % NKH;
    int mt = t2 / NKH;
    int m  = mt * 16 + (l & 15);
    int k0 = ks * 32 + ((l >> 4) << 3);
    float x[8];
    if (m < NSPAN && k0 + 8 <= DSPAN) {       // g rows 16B-aligned
      float4 f0 = *(const float4*)&g[m * DSPAN + k0];
      float4 f1 = *(const float4*)&g[m * DSPAN + k0 + 4];
      x[0]=f0.x; x[1]=f0.y; x[2]=f0.z; x[3]=f0.w;
      x[4]=f1.x; x[5]=f1.y; x[6]=f1.z; x[7]=f1.w;
    } else {
#pragma unroll
      for (int i = 0; i < 8; ++i) {
        int k = k0 + i;
        x[i] = (m < NSPAN && k < DSPAN) ? g[m * DSPAN + k] : 0.f;
      }
    }
    short v1[8], v2[8];
#pragma unroll
    for (int i = 0; i < 8; ++i) { v1[i] = f2bf(x[i]); v2[i] = f2bf(x[i] * x[i]); }
    size_t o1 = ((size_t)(mt * NKS + ks) * 64 + l) * 8;
    *(bf16x8*)(A_fr + o1) = *(const bf16x8*)v1;
    *(bf16x8*)(A_fr + o1 + (size_t)NKH * 512) = *(const bf16x8*)v2;
  } else if (b < GA + GB) {                   // ---- Wc fragments ----
    int tid = (b - GA) * 256 + t;             // 390*256 = 20*78*64 exact
    int l  = tid & 63;
    int t2 = tid >> 6;
    int ks = t2 % NKS;
    int nt = t2 / NKS;
    int n  = nt * 16 + (l & 15);
    int k0 = ks * 32 + ((l >> 4) << 3);
    short v[8];
#pragma unroll
    for (int i = 0; i < 8; ++i) {
      int k = k0 + i;
      float x = 0.f;
      if (n < HID) {
        if (k < DSPAN)                     x = W1[k * HID + n];
      } else if (n >= HP && n < HP + HID) {
        int j = n - HP;
        if (k < DSPAN)                     x = W1[(DSPAN + k) * HID + j];
        else if (k >= 1248 && k < 2468)    x = W1[(1192 + k) * HID + j];
      }
      v[i] = f2bf(x);
    }
    *(bf16x8*)(Wc_fr + (size_t)tid * 8) = *(const bf16x8*)v;
  } else if (b < GA + GB + GC) {              // ---- combined phi table (bf16) ----
    int idx = (b - GA - GB) * 256 + t;
    if (idx < NCMB * HP) {
      int c = idx / HP;
      int j = idx - c * HP;
      float v = 0.f;
      if (j < HID) {
        int si = c % 3;
        int t2 = c / 3;
        int gi = t2 % 7;
        int bi = t2 / 7;
        v = b1[j];
        const float* dp = de + bi * 20;
        const float* gp = ge + gi * 20;
        const float* sp = se + si * 20;
#pragma unroll
        for (int e = 0; e < 20; ++e) {
          v += dp[e] * W1[(3660 + e) * HID + j];
          v += gp[e] * W1[(3680 + e) * HID + j];
          v += sp[e] * W1[(3700 + e) * HID + j];
        }
      }
      combo[idx] = f2bf(v);
    }
  } else {                                    // ---- W2 fragments ----
    int tid = (b - GA - GB - GC) * 256 + t;
    if (tid < 3200) {
      int l  = tid & 63;
      int t2 = tid >> 6;
      int ks = t2 % 5;
      int jt = t2 / 5;
      int n  = jt * 16 + (l & 15);
      int k0 = ks * 32 + ((l >> 4) << 3);
      short v[8];
#pragma unroll
      for (int i = 0; i < 8; ++i) {
        int k = k0 + i;
        float x = (k < HID && n < HID) ? W2[k * HID + n] : 0.f;
        v[i] = f2bf(x);
      }
      *(bf16x8*)(W2_fr + (size_t)tid * 8) = *(const bf16x8*)v;
    }
  }
}

// ---------- span GEMM: Tpart[z] = A_cat @ Wc (k-chunk z), plain stores ----------
__global__ __launch_bounds__(256)
void span_gemm(const short* __restrict__ A_fr, const short* __restrict__ Wc_fr,
               float* __restrict__ Tpart) {
  int t = threadIdx.x, w = t >> 6, l = t & 63;
  int mt  = blockIdx.y * 4 + w;
  int ntb = blockIdx.x * 4;
  int ksb = blockIdx.z * 13;
  float* Tp = Tpart + (size_t)blockIdx.z * TSZ;
  const short* pa = A_fr + ((size_t)(mt * NKS + ksb) * 64 + l) * 8;
  const short* pb = Wc_fr + ((size_t)(ntb * NKS + ksb) * 64 + l) * 8;
  f32x4 a0 = {0.f, 0.f, 0.f, 0.f}, a1 = a0, a2 = a0, a3 = a0;
#pragma unroll
  for (int ks = 0; ks < 13; ++ks) {
    bf16x8 a  = *(const bf16x8*)pa;
    bf16x8 b0 = *(const bf16x8*)pb;
    bf16x8 b1 = *(const bf16x8*)(pb + (size_t)NKS * 512);
    bf16x8 b2 = *(const bf16x8*)(pb + (size_t)2 * NKS * 512);
    bf16x8 b3 = *(const bf16x8*)(pb + (size_t)3 * NKS * 512);
    a0 = __builtin_amdgcn_mfma_f32_16x16x32_bf16(a, b0, a0, 0, 0, 0);
    a1 = __builtin_amdgcn_mfma_f32_16x16x32_bf16(a, b1, a1, 0, 0, 0);
    a2 = __builtin_amdgcn_mfma_f32_16x16x32_bf16(a, b2, a2, 0, 0, 0);
    a3 = __builtin_amdgcn_mfma_f32_16x16x32_bf16(a, b3, a3, 0, 0, 0);
    pa += 512; pb += 512;
  }
  int col = l & 15, row4 = (l >> 4) << 2;
  f32x4 acc[4] = {a0, a1, a2, a3};
#pragma unroll
  for (int r = 0; r < 4; ++r) {
    int m = mt * 16 + row4 + r;
    if (m < NSPAN) {
#pragma unroll
      for (int j = 0; j < 4; ++j)
        Tp[m * TW + (ntb + j) * 16 + col] = acc[j][r];
    }
  }
}

// ---------- reduce_T: sum 6 partials -> bf16 Tb ----------
__global__ __launch_bounds__(256)
void reduce_T(const float* __restrict__ Tpart, short* __restrict__ Tb) {
  int i = (blockIdx.x * 256 + threadIdx.x) * 4;   // 625 blocks: 160000 float4 exact
  float4 s = *(const float4*)(Tpart + i);
#pragma unroll
  for (int z = 1; z < KC; ++z) {
    float4 v = *(const float4*)(Tpart + (size_t)z * TSZ + i);
    s.x += v.x; s.y += v.y; s.z += v.z; s.w += v.w;
  }
  bf16x4 r;
  r[0] = f2bf(s.x); r[1] = f2bf(s.y); r[2] = f2bf(s.z); r[3] = f2bf(s.w);
  *(bf16x4*)(Tb + i) = r;
}

// ---------- pair kernel: R4 grouped-LDS gather (bf16) -> MFMA -> score ----------
__global__ __launch_bounds__(256)
void pair_kernel(const short* __restrict__ Tb, const short* __restrict__ combo,
                 const short* __restrict__ W2_fr,
                 const float* __restrict__ b2, const float* __restrict__ W3,
                 const float* __restrict__ b3, const float* __restrict__ s_m,
                 const int* __restrict__ m_ids, const int* __restrict__ a_ids,
                 const int* __restrict__ dist, const int* __restrict__ genre,
                 const int* __restrict__ spk, float* __restrict__ out) {
  __shared__ short h1s[64 * H1S];
  __shared__ float w3s[HP], b2s[HP], sm2[64];
  __shared__ int mi[64], ai[64], co[64];

  int t = threadIdx.x;
  int base = blockIdx.x * 64;

  if (t < 64) {
    int p = base + t;
    int m = m_ids[p], a = a_ids[p];
    mi[t] = m; ai[t] = a;
    sm2[t] = s_m[m] + s_m[a];
    int d = dist[p];
    int bb = (d >= 2) + (d >= 3) + (d >= 4) + (d >= 5) + (d >= 8) +
             (d >= 16) + (d >= 32) + (d >= 64);
    co[t] = ((bb * 7 + genre[p]) * 3 + spk[p]) * HP;
  }
  if (t < HP) {
    w3s[t] = (t < HID) ? W3[t] : 0.f;
    b2s[t] = (t < HID) ? b2[t] : 0.f;
  }
  float b3v = b3[0];
  __syncthreads();

  // h1 = relu(Tb_A[m] + Tb_B[a] + combo): grouped grid-stride, 16B bf16x8 chunks
  for (int idx = t; idx < 64 * 20; idx += 256) {
    int p = idx / 20;
    int j = (idx - p * 20) * 8;
    bf16x8 va = *(const bf16x8*)&Tb[mi[p] * TW + j];
    bf16x8 vb = *(const bf16x8*)&Tb[ai[p] * TW + HP + j];
    bf16x8 vc = *(const bf16x8*)&combo[co[p] + j];
    short r[8];
#pragma unroll
    for (int i = 0; i < 8; ++i)
      r[i] = f2bf(fmaxf(bf2f(va[i]) + bf2f(vb[i]) + bf2f(vc[i]), 0.f));
    *(bf16x8*)&h1s[p * H1S + j] = *(const bf16x8*)r;
  }
  __syncthreads();

  int w = t >> 6, l = t & 63;
  const short* hrow = h1s + (w * 16 + (l & 15)) * H1S + ((l >> 4) << 3);
  bf16x8 af[5];
#pragma unroll
  for (int ks = 0; ks < 5; ++ks) af[ks] = *(const bf16x8*)(hrow + ks * 32);

  f32x4 acc[10];
#pragma unroll
  for (int jt = 0; jt < 10; ++jt) acc[jt] = {0.f, 0.f, 0.f, 0.f};

  const short* pw = W2_fr + l * 8;
#pragma unroll
  for (int jt = 0; jt < 10; ++jt) {
#pragma unroll
    for (int ks = 0; ks < 5; ++ks) {
      bf16x8 bfr = *(const bf16x8*)(pw + (size_t)(jt * 5 + ks) * 512);
      acc[jt] = __builtin_amdgcn_mfma_f32_16x16x32_bf16(af[ks], bfr, acc[jt], 0, 0, 0);
    }
  }

  // epilogue: relu(h2 + b2) . W3, reduce over the 16 col-lanes
  float part[4] = {0.f, 0.f, 0.f, 0.f};
  int cl = l & 15;
#pragma unroll
  for (int jt = 0; jt < 10; ++jt) {
    int n = jt * 16 + cl;
    float w3v = w3s[n], b2v = b2s[n];
#pragma unroll
    for (int r = 0; r < 4; ++r) part[r] += fmaxf(acc[jt][r] + b2v, 0.f) * w3v;
  }
#pragma unroll
  for (int off = 8; off >= 1; off >>= 1) {
#pragma unroll
    for (int r = 0; r < 4; ++r) part[r] += __shfl_xor(part[r], off, 64);
  }
  if (cl == 0) {
    int rowb = (l >> 4) << 2;
#pragma unroll
    for (int r = 0; r < 4; ++r) {
      int pl = w * 16 + rowb + r;
      out[base + pl] = sm2[pl] + part[r] + b3v;
    }
  }
}

extern "C" void kernel_launch(void* const* d_in, const int* in_sizes, int n_in,
                              void* d_out, int out_size, void* d_ws, size_t ws_size,
                              hipStream_t stream) {
  const float* g     = (const float*)d_in[0];
  const float* s_m   = (const float*)d_in[1];
  const int*   m_ids = (const int*)d_in[2];
  const int*   a_ids = (const int*)d_in[3];
  const int*   dist  = (const int*)d_in[4];
  const int*   genre = (const int*)d_in[5];
  const int*   spk   = (const int*)d_in[6];
  const float* de    = (const float*)d_in[7];
  const float* ge    = (const float*)d_in[8];
  const float* se    = (const float*)d_in[9];
  const float* W1    = (const float*)d_in[10];
  const float* b1    = (const float*)d_in[11];
  const float* W2    = (const float*)d_in[12];
  const float* b2    = (const float*)d_in[13];
  const float* W3    = (const float*)d_in[14];
  const float* b3    = (const float*)d_in[15];
  float* out = (float*)d_out;

  float* Tpart = (float*)d_ws;                    // 6 * 640000 f32 = 15.36 MB
  short* Tb    = (short*)(Tpart + (size_t)KC * TSZ); // 640000 bf16 = 1.28 MB
  short* combo = Tb + TSZ;                        // 189*160 bf16
  short* A_fr  = combo + NCMB * HP;               // 128*78*512 bf16 = 10.22 MB
  short* Wc_fr = A_fr + (size_t)NMT * NKS * 512;  // 20*78*512 bf16 = 1.60 MB
  short* W2_fr = Wc_fr + (size_t)NNT * NKS * 512; // 3200*8 bf16

  prep_all<<<GA + GB + GC + GD, 256, 0, stream>>>(
      g, W1, b1, de, ge, se, W2, A_fr, Wc_fr, combo, W2_fr);
  span_gemm<<<dim3(5, 32, KC), 256, 0, stream>>>(A_fr, Wc_fr, Tpart);
  reduce_T<<<625, 256, 0, stream>>>(Tpart, Tb);
  pair_kernel<<<NPAIR / 64, 256, 0, stream>>>(Tb, combo, W2_fr, b2, W3, b3, s_m,
                                              m_ids, a_ids, dist, genre, spk, out);
}